// Round 1
// baseline (190.563 us; speedup 1.0000x reference)
//
#include <hip/hip_runtime.h>
#include <hip/hip_bf16.h>

// Taylor subpixel refinement: N=64, P=17, H=W=192.
// One thread per keypoint; 13 scattered heatmap gathers + 2x2 Hessian solve.
// Latency-bound; total useful traffic < 1 MB.

__global__ void taylor_kernel(const float* __restrict__ coords,
                              const float* __restrict__ heat,
                              float* __restrict__ out,
                              int NP, int H, int W) {
    int i = blockIdx.x * blockDim.x + threadIdx.x;
    if (i >= NP) return;

    float cx = coords[2 * i];       // x in [0,1)
    float cy = coords[2 * i + 1];   // y in [0,1)
    float x = cx * (float)W;        // pixel coords
    float y = cy * (float)H;

    int px = (int)x;                // truncation (positive -> floor), matches astype(int32)
    int py = (int)y;
    bool inb = (px > 1) && (px < W - 2) && (py > 1) && (py < H - 2);
    int pxc = min(max(px, 2), W - 3);
    int pyc = min(max(py, 2), H - 3);

    const float* __restrict__ hm = heat + (size_t)i * (size_t)(H * W);

    // log of heatmap value at (pyc+dy, pxc+dx), with 0 -> 1e-10 guard
    auto g = [&](int dy, int dx) -> float {
        float v = hm[(pyc + dy) * W + (pxc + dx)];
        v = (v == 0.0f) ? 1e-10f : v;
        return logf(v);
    };

    float dx_ = 0.5f * (g(0, 1) - g(0, -1));
    float dy_ = 0.5f * (g(1, 0) - g(-1, 0));
    float g00 = g(0, 0);
    float dxx = 0.25f * (g(0, 2) - 2.0f * g00 + g(0, -2));
    float dxy = 0.25f * (g(1, 1) - g(-1, 1) - g(1, -1) + g(-1, -1));
    float dyy = 0.25f * (g(2, 0) - 2.0f * g00 + g(-2, 0));

    float det = dxx * dyy - dxy * dxy;
    bool ok = inb && (det != 0.0f);
    float sd = ok ? det : 1.0f;
    float offx = -(dyy * dx_ - dxy * dy_) / sd;
    float offy = -(dxx * dy_ - dxy * dx_) / sd;
    if (ok) {
        x += offx;
        y += offy;
    }

    // out = (xy / dims)[..., ::-1]  ->  (y/H, x/W)
    out[2 * i]     = y / (float)H;
    out[2 * i + 1] = x / (float)W;
}

extern "C" void kernel_launch(void* const* d_in, const int* in_sizes, int n_in,
                              void* d_out, int out_size, void* d_ws, size_t ws_size,
                              hipStream_t stream) {
    const float* coords = (const float*)d_in[0];   // [N,P,2] fp32
    const float* heat   = (const float*)d_in[1];   // [N,P,H,W] fp32
    float* out = (float*)d_out;                    // [N,P,2] fp32

    int NP = in_sizes[0] / 2;                      // 64*17 = 1088
    long long hw = (long long)in_sizes[1] / (long long)NP;  // H*W = 36864
    // H == W for this problem (192x192); derive to stay robust.
    int W = 192, H = 192;
    if (hw != 36864) {
        // fallback: assume square
        int s = (int)(sqrt((double)hw) + 0.5);
        W = s; H = s;
    }

    int block = 256;
    int grid = (NP + block - 1) / block;
    taylor_kernel<<<grid, block, 0, stream>>>(coords, heat, out, NP, H, W);
}